// Round 3
// baseline (109.156 us; speedup 1.0000x reference)
//
#include <hip/hip_runtime.h>

#define BATCH  256
#define TLEN   8192
#define TPB1   1024                     // fused / apply block size
#define LUTN   1024
#define RECN   304                      // per-batch folded param record (floats)
#define VLO    -8.0f
#define H      0.015625f                // 16 / 1024
#define INVH   64.0f
#define UOFF   512.0f                   // -VLO / H
#define UMAX   1022.999f                // clamp so i+1 <= 1023
#define SQRT7  2.6457513110645906f
#define C1     2.6457513110645906e-6f   // sqrt(7) * 1e-6

// Param record p[304] (proven layout, prior session rounds 4-11):
//   0: la'  (8) = (w1-mean)*sc1*sqrt7      8: lc' (8) = (b1-mean)*sc1*sqrt7
//  16: sb1  (8)                           24: A, 2B, C, b5
//  32 + 88*l (l=0..2): wc(64 centered), cb(8), sc'(8, *sqrt7), sb(8)
// 296: w5 (8)
// Identity: sc*d/(sqrt(var/7)+1e-6) == d*rcp(sqrt(var)+sqrt7*1e-6)*(sc*sqrt7)
// Batch-dependent slots: 0-23, 104-119, 192-207, 280-295.  Rest is shared.

__device__ __forceinline__ float rowmean8(const float* __restrict__ p) {
    return (((p[0] + p[1]) + (p[2] + p[3])) + ((p[4] + p[5]) + (p[6] + p[7]))) * 0.125f;
}
__device__ __forceinline__ float lrelu(float t) { return fmaxf(t, 0.01f * t); }

// ---------------------------------------------------------------------------
// Phase D body: compute one LUT point from the p[304] record in LDS.
// ---------------------------------------------------------------------------
__device__ __forceinline__ float lut_point_from_p(const float* p, const int tid)
{
    const float4 q = *(const float4*)(p + 24);          // A, 2B, C, b5
    const float vv = VLO + (float)tid * H;

    float h[8];
    {
        const float4 a0 = *(const float4*)(p);
        const float4 a1 = *(const float4*)(p + 4);
        const float4 c0 = *(const float4*)(p + 8);
        const float4 c1 = *(const float4*)(p + 12);
        const float4 s0 = *(const float4*)(p + 16);
        const float4 s1 = *(const float4*)(p + 20);
        const float laa[8] = {a0.x,a0.y,a0.z,a0.w,a1.x,a1.y,a1.z,a1.w};
        const float lcc[8] = {c0.x,c0.y,c0.z,c0.w,c1.x,c1.y,c1.z,c1.w};
        const float sb1[8] = {s0.x,s0.y,s0.z,s0.w,s1.x,s1.y,s1.z,s1.w};
        const float var = fmaxf(fmaf(vv, fmaf(vv, q.x, q.y), q.z), 0.f);
        const float r   = __builtin_amdgcn_rcpf(__builtin_amdgcn_sqrtf(var) + C1);
        #pragma unroll
        for (int j = 0; j < 8; ++j) {
            const float d = fmaf(vv, laa[j], lcc[j]);
            h[j] = lrelu(fmaf(d, r, sb1[j]));
        }
    }

    #pragma unroll 1
    for (int l = 0; l < 3; ++l) {
        const float* __restrict__ w = p + 32 + l * 88;

        float g[8];
        {
            const float4 c0 = *(const float4*)(w + 64);
            const float4 c1 = *(const float4*)(w + 68);
            const float4 wa = *(const float4*)(w);
            const float4 wb = *(const float4*)(w + 4);
            const float hk = h[0];
            g[0] = fmaf(hk, wa.x, c0.x); g[1] = fmaf(hk, wa.y, c0.y);
            g[2] = fmaf(hk, wa.z, c0.z); g[3] = fmaf(hk, wa.w, c0.w);
            g[4] = fmaf(hk, wb.x, c1.x); g[5] = fmaf(hk, wb.y, c1.y);
            g[6] = fmaf(hk, wb.z, c1.z); g[7] = fmaf(hk, wb.w, c1.w);
        }
        #pragma unroll
        for (int k = 1; k < 8; ++k) {
            const float4 wa = *(const float4*)(w + k * 8);
            const float4 wb = *(const float4*)(w + k * 8 + 4);
            const float hk = h[k];
            g[0] = fmaf(hk, wa.x, g[0]); g[1] = fmaf(hk, wa.y, g[1]);
            g[2] = fmaf(hk, wa.z, g[2]); g[3] = fmaf(hk, wa.w, g[3]);
            g[4] = fmaf(hk, wb.x, g[4]); g[5] = fmaf(hk, wb.y, g[5]);
            g[6] = fmaf(hk, wb.z, g[6]); g[7] = fmaf(hk, wb.w, g[7]);
        }
        {
            const float4 s0 = *(const float4*)(w + 72);
            const float4 s1 = *(const float4*)(w + 76);
            const float4 t0 = *(const float4*)(w + 80);
            const float4 t1 = *(const float4*)(w + 84);
            const float sc[8] = {s0.x,s0.y,s0.z,s0.w,s1.x,s1.y,s1.z,s1.w};
            const float sb[8] = {t0.x,t0.y,t0.z,t0.w,t1.x,t1.y,t1.z,t1.w};
            float var = 0.f;
            #pragma unroll
            for (int j = 0; j < 8; ++j) var = fmaf(g[j], g[j], var);
            const float r = __builtin_amdgcn_rcpf(__builtin_amdgcn_sqrtf(var) + C1);
            #pragma unroll
            for (int j = 0; j < 8; ++j)
                h[j] = lrelu(fmaf(g[j] * r, sc[j], sb[j]));
        }
    }

    {
        const float4 f0 = *(const float4*)(p + 296);
        const float4 f1 = *(const float4*)(p + 300);
        const float w5v[8] = {f0.x,f0.y,f0.z,f0.w,f1.x,f1.y,f1.z,f1.w};
        float a = q.w;
        #pragma unroll
        for (int k = 0; k < 8; ++k) a = fmaf(h[k], w5v[k], a);
        return lrelu(a);
    }
}

// ---------------------------------------------------------------------------
// Kernel 1: batched style MLP + fold.  16 blocks x 1024 threads, 16 batches
// per block.  Weights staged ONCE per block (not once per batch); every
// thread productive in every MLP phase.  Writes folded p[304] records.
// ---------------------------------------------------------------------------
__global__ __launch_bounds__(1024, 4) void style_kernel(
    const float* __restrict__ metadata,
    const float* __restrict__ mw1, const float* __restrict__ mb1,
    const float* __restrict__ mw2, const float* __restrict__ mb2,
    const float* __restrict__ mw3, const float* __restrict__ mb3,
    const float* __restrict__ w1, const float* __restrict__ b1,
    const float* __restrict__ w2, const float* __restrict__ b2,
    const float* __restrict__ w3, const float* __restrict__ b3,
    const float* __restrict__ w4, const float* __restrict__ b4,
    const float* __restrict__ w5, const float* __restrict__ b5,
    float* __restrict__ recs)
{
    __shared__ float smw1[1024];        // 16x64
    __shared__ float smw2[8192];        // 64x128
    __shared__ float smw3[8192];        // 128x64
    __shared__ float smd[256];          // 16 batches x 16
    __shared__ float sh1[1024];         // 16 x 64
    __shared__ float sh2[2048];         // 16 x 128
    __shared__ float ss[1024];          // 16 x 64
    __shared__ float tpl[RECN];         // shared record template
    __shared__ float sla[8], slc[8];

    const int tid = threadIdx.x;
    const int b0  = blockIdx.x * 16;    // first batch of this block

    // ---- stage weights + metadata (coalesced float4) ----
    float4 t2a = ((const float4*)mw2)[tid];
    float4 t2b = ((const float4*)mw2)[tid + 1024];
    float4 t3a = ((const float4*)mw3)[tid];
    float4 t3b = ((const float4*)mw3)[tid + 1024];
    ((float4*)smw2)[tid]        = t2a;
    ((float4*)smw2)[tid + 1024] = t2b;
    ((float4*)smw3)[tid]        = t3a;
    ((float4*)smw3)[tid + 1024] = t3b;
    if (tid < 256) ((float4*)smw1)[tid] = ((const float4*)mw1)[tid];
    if (tid >= 64 && tid < 128)
        ((float4*)smd)[tid - 64] = ((const float4*)metadata)[blockIdx.x * 64 + (tid - 64)];

    // ---- batch-independent record template (runs concurrently w/ staging) ----
    if (tid >= 256 && tid < 320) {
        int i = tid - 256; tpl[32 + i]  = w2[i] - rowmean8(w2 + (i & 56));
    } else if (tid >= 320 && tid < 384) {
        int i = tid - 320; tpl[120 + i] = w3[i] - rowmean8(w3 + (i & 56));
    } else if (tid >= 384 && tid < 448) {
        int i = tid - 384; tpl[208 + i] = w4[i] - rowmean8(w4 + (i & 56));
    } else if (tid >= 448 && tid < 456) {
        int j = tid - 448; sla[j] = w1[j] - rowmean8(w1); slc[j] = b1[j] - rowmean8(b1);
    } else if (tid >= 456 && tid < 464) {
        int j = tid - 456; tpl[96 + j]  = b2[j] - rowmean8(b2);
    } else if (tid >= 464 && tid < 472) {
        int j = tid - 464; tpl[184 + j] = b3[j] - rowmean8(b3);
    } else if (tid >= 472 && tid < 480) {
        int j = tid - 472; tpl[272 + j] = b4[j] - rowmean8(b4);
    } else if (tid >= 480 && tid < 488) {
        int j = tid - 480; tpl[296 + j] = w5[j];
    } else if (tid == 488) {
        tpl[27] = b5[0];
    } else if (tid >= 489 && tid < 493) {
        tpl[28 + (tid - 489)] = 0.f;    // never read, but keep defined
    }
    __syncthreads();

    // ---- h1: 16x64 outputs, 1 per thread ----
    {
        const int b = tid >> 6, j = tid & 63;
        float a = mb1[j];
        #pragma unroll
        for (int k = 0; k < 16; ++k) a = fmaf(smd[b * 16 + k], smw1[k * 64 + j], a);
        sh1[tid] = fmaxf(a, 0.f);
        if (tid == 0) {                 // A, 2B, C (batch-independent), sla/slc ready
            float A = 0.f, Bv = 0.f, Cv = 0.f;
            #pragma unroll
            for (int j2 = 0; j2 < 8; ++j2) {
                A  = fmaf(sla[j2], sla[j2], A);
                Bv = fmaf(sla[j2], slc[j2], Bv);
                Cv = fmaf(slc[j2], slc[j2], Cv);
            }
            tpl[24] = A; tpl[25] = 2.f * Bv; tpl[26] = Cv;
        }
    }
    __syncthreads();

    // ---- h2: 16x128 outputs, 2 per thread ----
    {
        const int b = tid >> 6, jj = tid & 63;
        float a0 = mb2[jj], a1 = mb2[jj + 64];
        #pragma unroll 16
        for (int k = 0; k < 64; ++k) {
            const float hv = sh1[b * 64 + k];
            a0 = fmaf(hv, smw2[k * 128 + jj], a0);
            a1 = fmaf(hv, smw2[k * 128 + jj + 64], a1);
        }
        sh2[b * 128 + jj]      = fmaxf(a0, 0.f);
        sh2[b * 128 + jj + 64] = fmaxf(a1, 0.f);
    }
    __syncthreads();

    // ---- s: 16x64 outputs, 1 per thread ----
    {
        const int b = tid >> 6, j = tid & 63;
        float a = mb3[j];
        #pragma unroll 16
        for (int k = 0; k < 128; ++k) a = fmaf(sh2[b * 128 + k], smw3[k * 64 + j], a);
        ss[tid] = a;                    // ss[b*64 + 16L + 2c]=scale, +1=bias
    }
    __syncthreads();

    // ---- fold + write records: 64 threads per batch ----
    {
        const int b = tid >> 6, t = tid & 63;
        const float* sb_ = ss + b * 64;
        float* rec = recs + (size_t)(b0 + b) * RECN;
        #pragma unroll
        for (int idx = t; idx < RECN; idx += 64) {
            float v = tpl[idx];
            const int j = idx & 7;
            if (idx < 8)                       v = sla[j] * (sb_[2 * j] * SQRT7);
            else if (idx < 16)                 v = slc[j] * (sb_[2 * j] * SQRT7);
            else if (idx < 24)                 v = sb_[2 * j + 1];
            else if (idx >= 104 && idx < 112)  v = sb_[16 + 2 * j] * SQRT7;
            else if (idx >= 112 && idx < 120)  v = sb_[16 + 2 * j + 1];
            else if (idx >= 192 && idx < 200)  v = sb_[32 + 2 * j] * SQRT7;
            else if (idx >= 200 && idx < 208)  v = sb_[32 + 2 * j + 1];
            else if (idx >= 280 && idx < 288)  v = sb_[48 + 2 * j] * SQRT7;
            else if (idx >= 288 && idx < 296)  v = sb_[48 + 2 * j + 1];
            rec[idx] = v;
        }
    }
}

// ---------------------------------------------------------------------------
// Kernel 2: fused LUT-build + apply, short chain.  One block per batch.
// Load p[304] record (76 float4, L2-hot) -> phase D -> interp.  x/out
// streaming hides under the (now short) chain.
// ---------------------------------------------------------------------------
__global__ __launch_bounds__(TPB1, 4) void fused_apply_kernel(
    const float* __restrict__ x, const float* __restrict__ recs,
    float* __restrict__ out)
{
    __shared__ float p[RECN];
    __shared__ float lut[LUTN];

    const int b   = blockIdx.x;
    const int tid = threadIdx.x;

    // prefetch x (2 float4/thread)
    const int base4 = b * (TLEN / 4) + tid;
    float4 vx0 = ((const float4*)x)[base4];
    float4 vx1 = ((const float4*)x)[base4 + TPB1];

    // stage record (304 floats = 76 float4)
    if (tid < 76) ((float4*)p)[tid] = ((const float4*)(recs + (size_t)b * RECN))[tid];
    __syncthreads();

    lut[tid] = lut_point_from_p(p, tid);
    __syncthreads();

    #pragma unroll
    for (int r = 0; r < 2; ++r) {
        const float4 v = r ? vx1 : vx0;
        const float vin[4] = {v.x, v.y, v.z, v.w};
        float vo[4];
        #pragma unroll
        for (int c = 0; c < 4; ++c) {
            float u = fmaf(vin[c], INVH, UOFF);             // (v - VLO) / H
            u = fminf(fmaxf(u, 0.0f), UMAX);
            const int   i = (int)u;
            const float f = u - (float)i;
            const float a = lut[i];
            const float d = lut[i + 1] - a;
            vo[c] = fmaf(f, d, a);
        }
        ((float4*)out)[base4 + r * TPB1] = make_float4(vo[0], vo[1], vo[2], vo[3]);
    }
}

// ---------------------------------------------------------------------------
// Fallback: round-0 proven fully-fused kernel (used only if workspace tiny).
// ---------------------------------------------------------------------------
__global__ __launch_bounds__(TPB1, 8) void adain_lut_fused_kernel(
    const float* __restrict__ x, const float* __restrict__ metadata,
    const float* __restrict__ mw1, const float* __restrict__ mb1,
    const float* __restrict__ mw2, const float* __restrict__ mb2,
    const float* __restrict__ mw3, const float* __restrict__ mb3,
    const float* __restrict__ w1, const float* __restrict__ b1,
    const float* __restrict__ w2, const float* __restrict__ b2,
    const float* __restrict__ w3, const float* __restrict__ b3,
    const float* __restrict__ w4, const float* __restrict__ b4,
    const float* __restrict__ w5, const float* __restrict__ b5,
    float* __restrict__ out)
{
    __shared__ float smw1[1024];
    __shared__ float smw2[8192];
    __shared__ float smw3[8192];
    __shared__ float md[16];
    __shared__ float h1[64];
    __shared__ float h2[128];
    __shared__ float s[64];
    __shared__ float la[8], lc[8];
    __shared__ float p[RECN];
    __shared__ float lut[LUTN];

    const int b   = blockIdx.x;
    const int tid = threadIdx.x;

    const int base4 = b * (TLEN / 4) + tid;
    float4 vx0 = ((const float4*)x)[base4];
    float4 vx1 = ((const float4*)x)[base4 + TPB1];

    float4 t2a = ((const float4*)mw2)[tid];
    float4 t2b = ((const float4*)mw2)[tid + TPB1];
    float4 t3a = ((const float4*)mw3)[tid];
    float4 t3b = ((const float4*)mw3)[tid + TPB1];
    float4 t1  = (tid < 256) ? ((const float4*)mw1)[tid] : make_float4(0.f, 0.f, 0.f, 0.f);

    ((float4*)smw2)[tid]        = t2a;
    ((float4*)smw2)[tid + TPB1] = t2b;
    ((float4*)smw3)[tid]        = t3a;
    ((float4*)smw3)[tid + TPB1] = t3b;
    if (tid < 256) ((float4*)smw1)[tid] = t1;

    if (tid < 16) {
        md[tid] = metadata[b * 16 + tid];
    } else if (tid >= 128 && tid < 192) {
        int i = tid - 128; p[32 + i]  = w2[i] - rowmean8(w2 + (i & 56));
    } else if (tid >= 192 && tid < 256) {
        int i = tid - 192; p[120 + i] = w3[i] - rowmean8(w3 + (i & 56));
    } else if (tid >= 256 && tid < 320) {
        int i = tid - 256; p[208 + i] = w4[i] - rowmean8(w4 + (i & 56));
    } else if (tid >= 320 && tid < 328) {
        int j = tid - 320; la[j] = w1[j] - rowmean8(w1); lc[j] = b1[j] - rowmean8(b1);
    } else if (tid >= 328 && tid < 336) {
        int j = tid - 328; p[96 + j]  = b2[j] - rowmean8(b2);
    } else if (tid >= 336 && tid < 344) {
        int j = tid - 336; p[184 + j] = b3[j] - rowmean8(b3);
    } else if (tid >= 344 && tid < 352) {
        int j = tid - 344; p[272 + j] = b4[j] - rowmean8(b4);
    } else if (tid >= 352 && tid < 360) {
        int j = tid - 352; p[296 + j] = w5[j];
    } else if (tid == 360) {
        p[27] = b5[0];
    }
    __syncthreads();

    if (tid < 64) {
        float a = mb1[tid];
        #pragma unroll
        for (int k = 0; k < 16; ++k) a = fmaf(md[k], smw1[k * 64 + tid], a);
        h1[tid] = fmaxf(a, 0.f);
    }
    __syncthreads();
    if (tid < 128) {
        float a = mb2[tid];
        #pragma unroll 16
        for (int k = 0; k < 64; ++k) a = fmaf(h1[k], smw2[k * 128 + tid], a);
        h2[tid] = fmaxf(a, 0.f);
    }
    __syncthreads();
    if (tid < 64) {
        float a = mb3[tid];
        #pragma unroll 16
        for (int k = 0; k < 128; ++k) a = fmaf(h2[k], smw3[k * 64 + tid], a);
        s[tid] = a;
    }
    __syncthreads();

    if (tid < 8) {
        const float sc1 = s[2 * tid] * SQRT7;
        p[tid]      = la[tid] * sc1;
        p[8 + tid]  = lc[tid] * sc1;
        p[16 + tid] = s[2 * tid + 1];
        p[104 + tid] = s[16 + 2 * tid] * SQRT7;  p[112 + tid] = s[16 + 2 * tid + 1];
        p[192 + tid] = s[32 + 2 * tid] * SQRT7;  p[200 + tid] = s[32 + 2 * tid + 1];
        p[280 + tid] = s[48 + 2 * tid] * SQRT7;  p[288 + tid] = s[48 + 2 * tid + 1];
    } else if (tid == 8) {
        float A = 0.f, Bv = 0.f, Cv = 0.f;
        #pragma unroll
        for (int j = 0; j < 8; ++j) {
            A  = fmaf(la[j], la[j], A);
            Bv = fmaf(la[j], lc[j], Bv);
            Cv = fmaf(lc[j], lc[j], Cv);
        }
        p[24] = A; p[25] = 2.f * Bv; p[26] = Cv;
    }
    __syncthreads();

    lut[tid] = lut_point_from_p(p, tid);
    __syncthreads();

    #pragma unroll
    for (int r = 0; r < 2; ++r) {
        const float4 v = r ? vx1 : vx0;
        const float vin[4] = {v.x, v.y, v.z, v.w};
        float vo[4];
        #pragma unroll
        for (int c = 0; c < 4; ++c) {
            float u = fmaf(vin[c], INVH, UOFF);
            u = fminf(fmaxf(u, 0.0f), UMAX);
            const int   i = (int)u;
            const float f = u - (float)i;
            const float a = lut[i];
            const float d = lut[i + 1] - a;
            vo[c] = fmaf(f, d, a);
        }
        ((float4*)out)[base4 + r * TPB1] = make_float4(vo[0], vo[1], vo[2], vo[3]);
    }
}

extern "C" void kernel_launch(void* const* d_in, const int* in_sizes, int n_in,
                              void* d_out, int out_size, void* d_ws, size_t ws_size,
                              hipStream_t stream)
{
    const float* x        = (const float*)d_in[0];
    const float* metadata = (const float*)d_in[1];
    const float* mw1      = (const float*)d_in[2];
    const float* mb1      = (const float*)d_in[3];
    const float* mw2      = (const float*)d_in[4];
    const float* mb2      = (const float*)d_in[5];
    const float* mw3      = (const float*)d_in[6];
    const float* mb3      = (const float*)d_in[7];
    const float* w1       = (const float*)d_in[8];
    const float* b1       = (const float*)d_in[9];
    const float* w2       = (const float*)d_in[10];
    const float* b2       = (const float*)d_in[11];
    const float* w3       = (const float*)d_in[12];
    const float* b3       = (const float*)d_in[13];
    const float* w4       = (const float*)d_in[14];
    const float* b4       = (const float*)d_in[15];
    const float* w5       = (const float*)d_in[16];
    const float* b5       = (const float*)d_in[17];

    const size_t rec_bytes = (size_t)BATCH * RECN * sizeof(float);   // 311 KB

    if (d_ws != nullptr && ws_size >= rec_bytes) {
        float* recs = (float*)d_ws;
        style_kernel<<<16, 1024, 0, stream>>>(
            metadata, mw1, mb1, mw2, mb2, mw3, mb3,
            w1, b1, w2, b2, w3, b3, w4, b4, w5, b5, recs);
        fused_apply_kernel<<<BATCH, TPB1, 0, stream>>>(x, recs, (float*)d_out);
    } else {
        adain_lut_fused_kernel<<<BATCH, TPB1, 0, stream>>>(
            x, metadata, mw1, mb1, mw2, mb2, mw3, mb3,
            w1, b1, w2, b2, w3, b3, w4, b4, w5, b5, (float*)d_out);
    }
}

// Round 4
// 101.422 us; speedup vs baseline: 1.0763x; 1.0763x over previous
//
#include <hip/hip_runtime.h>

#define BATCH  256
#define TLEN   8192
#define TPB    1024
#define LUTN   1024
#define VLO    -8.0f
#define H      0.015625f                // 16 / 1024
#define INVH   64.0f
#define UOFF   512.0f                   // -VLO / H
#define UMAX   1022.999f                // clamp so i+1 <= 1023
#define SQRT7  2.6457513110645906f
#define C1     2.6457513110645906e-6f   // sqrt(7) * 1e-6

// Batch-dependent LDS record p[76]:
//   0: la' (8) = (w1-mean)*sc1*sqrt7    8: lc' (8) = (b1-mean)*sc1*sqrt7
//  16: sb1 (8)                         24: A, 2B, C, b5
//  28+16l: sc'_l (8, *sqrt7)           36+16l: sb_l (8)     (l = 0..2)
// Batch-INDEPENDENT weights (w2/w3/w4/b2/b3/b4/w5) are fetched in phase D
// directly from global args at uniform indices -> scalar loads (s_load),
// with mean-centering folded analytically:
//   g[j] = a[j] - mean_j(a),  a[j] = sum_k h_k * w_raw[k][j] + b_raw[j]
// Identity: sc*d/(sqrt(var/7)+1e-6) == d*rcp(sqrt(var)+sqrt7*1e-6)*(sc*sqrt7)

__device__ __forceinline__ float rowmean8(const float* __restrict__ p) {
    return (((p[0] + p[1]) + (p[2] + p[3])) + ((p[4] + p[5]) + (p[6] + p[7]))) * 0.125f;
}
__device__ __forceinline__ float lrelu(float t) { return fmaxf(t, 0.01f * t); }

// One AdaIN-MLP layer: raw weights from GLOBAL (uniform -> s_load),
// style scale/bias from LDS (scp[0..7] = sc*sqrt7, scp[8..15] = sb).
__device__ __forceinline__ void adain_layer(
    float h[8], const float* __restrict__ wl, const float* __restrict__ bl,
    const float* scp)
{
    float a[8];
    #pragma unroll
    for (int j = 0; j < 8; ++j) a[j] = bl[j];
    #pragma unroll
    for (int k = 0; k < 8; ++k) {
        const float hk = h[k];
        #pragma unroll
        for (int j = 0; j < 8; ++j) a[j] = fmaf(hk, wl[k * 8 + j], a[j]);
    }
    const float mu = (((a[0] + a[1]) + (a[2] + a[3])) +
                      ((a[4] + a[5]) + (a[6] + a[7]))) * 0.125f;
    float g[8], var = 0.f;
    #pragma unroll
    for (int j = 0; j < 8; ++j) { g[j] = a[j] - mu; var = fmaf(g[j], g[j], var); }
    const float r = __builtin_amdgcn_rcpf(__builtin_amdgcn_sqrtf(var) + C1);
    const float4 s0 = *(const float4*)(scp);
    const float4 s1 = *(const float4*)(scp + 4);
    const float4 t0 = *(const float4*)(scp + 8);
    const float4 t1 = *(const float4*)(scp + 12);
    const float sc[8] = {s0.x,s0.y,s0.z,s0.w,s1.x,s1.y,s1.z,s1.w};
    const float sb[8] = {t0.x,t0.y,t0.z,t0.w,t1.x,t1.y,t1.z,t1.w};
    #pragma unroll
    for (int j = 0; j < 8; ++j)
        h[j] = lrelu(fmaf(g[j] * r, sc[j], sb[j]));
}

// Single fused kernel (R0 structure, single launch): stage MLP weights ->
// style MLP -> fold batch-dependent params -> LUT (1 pt/thread, weights via
// scalar loads) -> interp apply (8 elems/thread).
__global__ __launch_bounds__(TPB, 8) void adain_lut_kernel(
    const float* __restrict__ x, const float* __restrict__ metadata,
    const float* __restrict__ mw1, const float* __restrict__ mb1,
    const float* __restrict__ mw2, const float* __restrict__ mb2,
    const float* __restrict__ mw3, const float* __restrict__ mb3,
    const float* __restrict__ w1, const float* __restrict__ b1,
    const float* __restrict__ w2, const float* __restrict__ b2,
    const float* __restrict__ w3, const float* __restrict__ b3,
    const float* __restrict__ w4, const float* __restrict__ b4,
    const float* __restrict__ w5, const float* __restrict__ b5,
    float* __restrict__ out)
{
    __shared__ float smw1[1024];        // 16x64
    __shared__ float smw2[8192];        // 64x128
    __shared__ float smw3[8192];        // 128x64
    __shared__ float md[16];
    __shared__ float h1[64];
    __shared__ float h2[128];
    __shared__ float s[64];
    __shared__ float la[8], lc[8];
    __shared__ float p[80];
    __shared__ float lut[LUTN];

    const int b   = blockIdx.x;
    const int tid = threadIdx.x;

    // ---- prefetch x (2 float4/thread) + issue all weight-staging loads NOW ----
    const int base4 = b * (TLEN / 4) + tid;
    float4 vx0 = ((const float4*)x)[base4];
    float4 vx1 = ((const float4*)x)[base4 + TPB];

    float4 t2a = ((const float4*)mw2)[tid];
    float4 t2b = ((const float4*)mw2)[tid + TPB];
    float4 t3a = ((const float4*)mw3)[tid];
    float4 t3b = ((const float4*)mw3)[tid + TPB];
    float4 t1  = (tid < 256) ? ((const float4*)mw1)[tid] : make_float4(0.f, 0.f, 0.f, 0.f);

    ((float4*)smw2)[tid]       = t2a;
    ((float4*)smw2)[tid + TPB] = t2b;
    ((float4*)smw3)[tid]       = t3a;
    ((float4*)smw3)[tid + TPB] = t3b;
    if (tid < 256) ((float4*)smw1)[tid] = t1;

    // ---- phase A: metadata load || w1/b1 centering (tiny) ----
    if (tid < 16) {
        md[tid] = metadata[b * 16 + tid];
    } else if (tid >= 64 && tid < 72) {
        int j = tid - 64; la[j] = w1[j] - rowmean8(w1); lc[j] = b1[j] - rowmean8(b1);
    } else if (tid == 80) {
        p[27] = b5[0];
    }
    __syncthreads();

    // ---- phase B: style MLP (16 -> 64 -> 128 -> 64), weights from LDS ----
    if (tid < 64) {
        float a = mb1[tid];
        #pragma unroll
        for (int k = 0; k < 16; ++k) a = fmaf(md[k], smw1[k * 64 + tid], a);
        h1[tid] = fmaxf(a, 0.f);
    }
    __syncthreads();
    if (tid < 128) {
        float a = mb2[tid];
        #pragma unroll 16
        for (int k = 0; k < 64; ++k) a = fmaf(h1[k], smw2[k * 128 + tid], a);
        h2[tid] = fmaxf(a, 0.f);
    }
    __syncthreads();
    if (tid < 64) {
        float a = mb3[tid];
        #pragma unroll 16
        for (int k = 0; k < 128; ++k) a = fmaf(h2[k], smw3[k * 64 + tid], a);
        s[tid] = a;                 // s[16L + 2c] = scale, s[16L + 2c + 1] = bias
    }
    __syncthreads();

    // ---- phase C: fold style into batch-dependent params ----
    if (tid < 8) {
        const float sc1 = s[2 * tid] * SQRT7;
        p[tid]      = la[tid] * sc1;
        p[8 + tid]  = lc[tid] * sc1;
        p[16 + tid] = s[2 * tid + 1];
        #pragma unroll
        for (int l = 0; l < 3; ++l) {
            p[28 + 16 * l + tid] = s[16 * (l + 1) + 2 * tid] * SQRT7;
            p[36 + 16 * l + tid] = s[16 * (l + 1) + 2 * tid + 1];
        }
    } else if (tid == 8) {
        float A = 0.f, Bv = 0.f, Cv = 0.f;
        #pragma unroll
        for (int j = 0; j < 8; ++j) {
            A  = fmaf(la[j], la[j], A);
            Bv = fmaf(la[j], lc[j], Bv);
            Cv = fmaf(lc[j], lc[j], Cv);
        }
        p[24] = A; p[25] = 2.f * Bv; p[26] = Cv;
    }
    __syncthreads();

    // ---- phase D: build LUT, ONE grid point per thread ----
    {
        const float4 q = *(const float4*)(p + 24);          // A, 2B, C, b5
        const float vv = VLO + (float)tid * H;

        float h[8];
        {
            const float4 a0 = *(const float4*)(p);
            const float4 a1 = *(const float4*)(p + 4);
            const float4 c0 = *(const float4*)(p + 8);
            const float4 c1 = *(const float4*)(p + 12);
            const float4 s0 = *(const float4*)(p + 16);
            const float4 s1 = *(const float4*)(p + 20);
            const float laa[8] = {a0.x,a0.y,a0.z,a0.w,a1.x,a1.y,a1.z,a1.w};
            const float lcc[8] = {c0.x,c0.y,c0.z,c0.w,c1.x,c1.y,c1.z,c1.w};
            const float sb1[8] = {s0.x,s0.y,s0.z,s0.w,s1.x,s1.y,s1.z,s1.w};
            const float var = fmaxf(fmaf(vv, fmaf(vv, q.x, q.y), q.z), 0.f);
            const float r   = __builtin_amdgcn_rcpf(__builtin_amdgcn_sqrtf(var) + C1);
            #pragma unroll
            for (int j = 0; j < 8; ++j) {
                const float d = fmaf(vv, laa[j], lcc[j]);
                h[j] = lrelu(fmaf(d, r, sb1[j]));
            }
        }

        // three 8x8 layers: raw weights via scalar loads from global
        adain_layer(h, w2, b2, p + 28);
        adain_layer(h, w3, b3, p + 44);
        adain_layer(h, w4, b4, p + 60);

        {
            float a = q.w;                                  // b5
            #pragma unroll
            for (int k = 0; k < 8; ++k) a = fmaf(h[k], w5[k], a);
            lut[tid] = lrelu(a);
        }
    }
    __syncthreads();

    // ---- phase E: interp the prefetched x, store (8 elems/thread) ----
    #pragma unroll
    for (int r = 0; r < 2; ++r) {
        const float4 v = r ? vx1 : vx0;
        const float vin[4] = {v.x, v.y, v.z, v.w};
        float vo[4];
        #pragma unroll
        for (int c = 0; c < 4; ++c) {
            float u = fmaf(vin[c], INVH, UOFF);             // (v - VLO) / H
            u = fminf(fmaxf(u, 0.0f), UMAX);
            const int   i = (int)u;
            const float f = u - (float)i;
            const float a = lut[i];
            const float d = lut[i + 1] - a;
            vo[c] = fmaf(f, d, a);
        }
        ((float4*)out)[base4 + r * TPB] = make_float4(vo[0], vo[1], vo[2], vo[3]);
    }
}

extern "C" void kernel_launch(void* const* d_in, const int* in_sizes, int n_in,
                              void* d_out, int out_size, void* d_ws, size_t ws_size,
                              hipStream_t stream)
{
    const float* x        = (const float*)d_in[0];
    const float* metadata = (const float*)d_in[1];
    const float* mw1      = (const float*)d_in[2];
    const float* mb1      = (const float*)d_in[3];
    const float* mw2      = (const float*)d_in[4];
    const float* mb2      = (const float*)d_in[5];
    const float* mw3      = (const float*)d_in[6];
    const float* mb3      = (const float*)d_in[7];
    const float* w1       = (const float*)d_in[8];
    const float* b1       = (const float*)d_in[9];
    const float* w2       = (const float*)d_in[10];
    const float* b2       = (const float*)d_in[11];
    const float* w3       = (const float*)d_in[12];
    const float* b3       = (const float*)d_in[13];
    const float* w4       = (const float*)d_in[14];
    const float* b4       = (const float*)d_in[15];
    const float* w5       = (const float*)d_in[16];
    const float* b5       = (const float*)d_in[17];

    adain_lut_kernel<<<BATCH, TPB, 0, stream>>>(
        x, metadata, mw1, mb1, mw2, mb2, mw3, mb3,
        w1, b1, w2, b2, w3, b3, w4, b4, w5, b5, (float*)d_out);
}